// Round 7
// baseline (533.144 us; speedup 1.0000x reference)
//
#include <hip/hip_runtime.h>

// QSScan: quantized selective scan (Mamba-style), int8-in-int32 + scalar scales.
// One wave per (b,d) scan, lane = timestep within a 64-step tile.
// Linear recurrence x_t = a_t*x_{t-1} + b_t solved per tile with an inclusive
// Kogge-Stone scan over the 64 lanes (6 shuffle steps x 16 states), carry via
// readlane(.,63). All global accesses are lane-consecutive (fully coalesced):
// no LDS tiles, no __syncthreads, no workspace, single pass.
//
// NOTE: __builtin_amdgcn_readlane is (int,int)->int; floats MUST be bit-cast,
// not value-converted (round 6 bug: float->int truncation zeroed the decays).

#define LOG2E 1.44269504088896340736f
#define LN2F  0.69314718055994530942f

constexpr int BATCH = 2;
constexpr int DIM   = 4096;
constexpr int LSEQ  = 2048;
constexpr int NST   = 16;
constexpr int SCANS = BATCH * DIM;   // 8192
constexpr int WPB   = 4;             // waves (scans) per block

__device__ __forceinline__ float readlane_f(float v, int lane) {
    union { float f; int i; } c;
    c.f = v;
    c.i = __builtin_amdgcn_readlane(c.i, lane);
    return c.f;
}

__global__ __launch_bounds__(256, 4) void qs_scan(
    const int* __restrict__ u,  const int* __restrict__ dt,
    const int* __restrict__ Bm, const int* __restrict__ Cm,
    const int* __restrict__ z,  const int* __restrict__ A_log,
    const int* __restrict__ Dv, const int* __restrict__ dt_bias,
    const float* __restrict__ u_sp,  const float* __restrict__ dt_sp,
    const float* __restrict__ A_sp,  const float* __restrict__ B_sp,
    const float* __restrict__ C_sp,  const float* __restrict__ z_sp,
    const float* __restrict__ D_sp,  const float* __restrict__ dtb_sp,
    float* __restrict__ out)
{
    const int lane = threadIdx.x & 63;
    const int wv   = threadIdx.x >> 6;
    const int scan = blockIdx.x * WPB + wv;       // 0..8191, one wave per scan
    const int d    = scan & (DIM - 1);
    const int bb   = scan >> 12;                  // batch index

    const float u_s = *u_sp, dt_s = *dt_sp, A_s = *A_sp, B_s = *B_sp;
    const float C_s = *C_sp, z_s  = *z_sp,  D_s = *D_sp, dtb_s = *dtb_sp;

    // A2[n] = A_n * log2(e), wave-uniform (depends on d,n): lane n computes its
    // own, broadcast via bit-cast readlane -> lives in SGPRs.
    float A2[NST];
    {
        const float a2v = -__builtin_amdgcn_exp2f(
            (float)A_log[d * NST + (lane & 15)] * (A_s * LOG2E)) * LOG2E;
#pragma unroll
        for (int n = 0; n < NST; ++n)
            A2[n] = readlane_f(a2v, n);
    }
    const float dtb = (float)dt_bias[d] * dtb_s;
    const float Dd  = (float)Dv[d] * D_s;

    const int* up = u  + (size_t)scan * LSEQ;
    const int* dp = dt + (size_t)scan * LSEQ;
    const int* zp = z  + (size_t)scan * LSEQ;
    float*     op = out + (size_t)scan * LSEQ;
    const int* Bb = Bm + (size_t)bb * NST * LSEQ;   // + n*LSEQ + t
    const int* Cb = Cm + (size_t)bb * NST * LSEQ;

    float xc[NST];                                   // carry: x at tile start
#pragma unroll
    for (int n = 0; n < NST; ++n) xc[n] = 0.f;

    for (int t0 = 0; t0 < LSEQ; t0 += 64) {
        const int t = t0 + lane;

        // ---- per-lane (per-timestep) scalars; all loads lane-consecutive
        const float uf    = (float)up[t] * u_s;
        const float sdt   = (float)dp[t] * dt_s + dtb;
        const float e     = __builtin_amdgcn_exp2f(sdt * LOG2E);
        const float delta = __builtin_amdgcn_logf(1.f + e) * LN2F;   // softplus
        const float w     = delta * uf * B_s;
        const float zf    = (float)zp[t] * z_s;
        const float gate  = zf * __builtin_amdgcn_rcpf(
                                1.f + __builtin_amdgcn_exp2f(-zf * LOG2E));

        // ---- per-state (a,b) for this timestep
        float a[NST], b[NST];
#pragma unroll
        for (int n = 0; n < NST; ++n) {
            a[n] = __builtin_amdgcn_exp2f(A2[n] * delta);
            b[n] = w * (float)Bb[n * LSEQ + t];
        }

        // ---- inclusive Kogge-Stone scan over 64 lanes (time order)
#pragma unroll
        for (int off = 1; off < 64; off <<= 1) {
#pragma unroll
            for (int n = 0; n < NST; ++n) {
                float ap = __shfl_up(a[n], off, 64);
                float bp = __shfl_up(b[n], off, 64);
                ap = (lane >= off) ? ap : 1.0f;
                bp = (lane >= off) ? bp : 0.0f;
                b[n] = __builtin_fmaf(a[n], bp, b[n]);
                a[n] = a[n] * ap;
            }
        }

        // ---- apply carry, output dot, update carry
        float y = 0.f;
#pragma unroll
        for (int n = 0; n < NST; ++n) {
            const float xn = __builtin_fmaf(a[n], xc[n], b[n]);  // x at step t
            y = __builtin_fmaf(xn, (float)Cb[n * LSEQ + t], y);
            xc[n] = readlane_f(xn, 63);                          // carry -> next tile
        }
        op[t] = __builtin_fmaf(y, C_s, Dd * uf) * gate;
    }
}

extern "C" void kernel_launch(void* const* d_in, const int* in_sizes, int n_in,
                              void* d_out, int out_size, void* d_ws, size_t ws_size,
                              hipStream_t stream) {
    dim3 grid(SCANS / WPB);   // 2048 blocks, one wave per scan
    dim3 block(64 * WPB);     // 256 threads
    qs_scan<<<grid, block, 0, stream>>>(
        (const int*)d_in[0], (const int*)d_in[1], (const int*)d_in[2],
        (const int*)d_in[3], (const int*)d_in[4], (const int*)d_in[5],
        (const int*)d_in[6], (const int*)d_in[7],
        (const float*)d_in[8],  (const float*)d_in[9],  (const float*)d_in[10],
        (const float*)d_in[11], (const float*)d_in[12], (const float*)d_in[13],
        (const float*)d_in[14], (const float*)d_in[15],
        (float*)d_out);
}

// Round 8
// 401.672 us; speedup vs baseline: 1.3273x; 1.3273x over previous
//
#include <hip/hip_runtime.h>

// QSScan: quantized selective scan (Mamba-style), int8-in-int32 + scalar scales.
// Chunked parallel linear recurrence, serial-in-thread, LDS-transpose-staged I/O:
//   phase1: thread=(scan,chunk): local scan from 0 over LC=64 steps -> X_end[16], S=sum(delta)
//   combine: thread=(scan,n): fold 32 chunks, P=exp2(A2*S) recomputed -> true init per chunk
//   phase2: thread=(scan,chunk): rerun from true init, emit y=(x.C)*C_s+D*u gated by silu(z)
// All global I/O goes through cooperative coalesced loads/stores + LDS transpose
// (u/dt/z staged as packed int8 bytes). Fixes R5's 3.7x fetch amplification while
// keeping R5's cheap serial compute (no shuffles: R7's KS scan was DS-pipe-bound).

#define LOG2E 1.44269504088896340736f
#define LN2F  0.69314718055994530942f

constexpr int BATCH = 2;
constexpr int DIM   = 4096;
constexpr int LSEQ  = 2048;
constexpr int NST   = 16;
constexpr int SCANS = BATCH * DIM;   // 8192
constexpr int K     = 32;            // chunks per scan
constexpr int LC    = LSEQ / K;      // 64 timesteps per chunk
constexpr int T     = 16;            // timesteps per staged sub-tile
constexpr int NSUB  = LC / T;        // 4 sub-tiles per chunk
constexpr int CPB   = 4;             // chunks per block
constexpr int SPB   = 64;            // scans per block  (256 threads = SPB x CPB)

__device__ __forceinline__ float softplus_f(float x) {
    float e = __builtin_amdgcn_exp2f(x * LOG2E);
    return __builtin_amdgcn_logf(1.f + e) * LN2F;
}

__device__ __forceinline__ int pack8(int4 v) {   // values in [-127,127]: exact
    return (v.x & 255) | ((v.y & 255) << 8) | ((v.z & 255) << 16) | ((v.w & 255) << 24);
}

#define LOAD_A2()                                                              \
    float A2[NST];                                                             \
    {                                                                          \
        const int4* ap = (const int4*)(A_log + (size_t)d * NST);               \
        int4 a0 = ap[0], a1 = ap[1], a2 = ap[2], a3 = ap[3];                   \
        const int ai[NST] = {a0.x,a0.y,a0.z,a0.w, a1.x,a1.y,a1.z,a1.w,         \
                             a2.x,a2.y,a2.z,a2.w, a3.x,a3.y,a3.z,a3.w};        \
        _Pragma("unroll")                                                      \
        for (int n = 0; n < NST; ++n)                                          \
            A2[n] = -__builtin_amdgcn_exp2f((float)ai[n] * (A_s * LOG2E)) * LOG2E; \
    }

// ---------------- Phase 1: per-chunk summaries (X_end, S) ----------------
__global__ __launch_bounds__(256, 4) void qs_phase1(
    const int* __restrict__ u,  const int* __restrict__ dt,
    const int* __restrict__ Bm, const int* __restrict__ A_log,
    const int* __restrict__ dt_bias,
    const float* __restrict__ u_sp, const float* __restrict__ dt_sp,
    const float* __restrict__ A_sp, const float* __restrict__ B_sp,
    const float* __restrict__ dtb_sp,
    float* __restrict__ Sbuf, float* __restrict__ Xbuf)
{
    const int tid = threadIdx.x;
    const int cg  = blockIdx.x >> 7;           // chunk-group 0..7
    const int sg  = blockIdx.x & 127;          // scan-group 0..127
    const int scan  = sg * SPB + (tid & 63);
    const int chunk = cg * CPB + (tid >> 6);
    const int d  = scan & (DIM - 1);
    const int bb = scan >> 12;                 // uniform per block (sg-aligned)

    // staged tiles: u/dt packed int8 [col 256][20B]; B tile [chunk][k][16n pad20]
    __shared__ int   su_i[256 * 5];
    __shared__ int   sd_i[256 * 5];
    __shared__ float tB[CPB * T * 20];

    const float u_s = *u_sp, dt_s = *dt_sp, A_s = *A_sp, B_s = *B_sp, dtb_s = *dtb_sp;
    LOAD_A2();
    const float dtb = (float)dt_bias[d] * dtb_s;

    // loader role: col r = p*64 + lr gets quad lq (16 ints per col per sub-tile)
    const int lr = tid >> 2, lq = tid & 3;
    size_t gb[4];
#pragma unroll
    for (int p = 0; p < 4; ++p)
        gb[p] = (size_t)(sg * SPB + lr) * LSEQ + (size_t)(cg * CPB + p) * LC + 4 * lq;
    const size_t bcb = ((size_t)bb * NST + (tid >> 4)) * LSEQ + cg * (CPB * LC) + (tid & 15);

    int4 pu[4], pd[4]; int pb[4];
    auto LOADG = [&](int tt0) {
#pragma unroll
        for (int p = 0; p < 4; ++p) {
            pu[p] = *(const int4*)(u  + gb[p] + tt0);
            pd[p] = *(const int4*)(dt + gb[p] + tt0);
        }
#pragma unroll
        for (int j = 0; j < 4; ++j) pb[j] = Bm[bcb + j * LC + tt0];
    };

    float x[NST];
#pragma unroll
    for (int n = 0; n < NST; ++n) x[n] = 0.f;
    float S = 0.f;
    const int bcol = tid * 20;             // byte offset of own column
    const int brow = (tid >> 6) * T;       // own chunk's B-tile row group

    LOADG(0);
    for (int st = 0; st < NSUB; ++st) {
#pragma unroll
        for (int p = 0; p < 4; ++p) {
            su_i[5 * (p * 64 + lr) + lq] = pack8(pu[p]);
            sd_i[5 * (p * 64 + lr) + lq] = pack8(pd[p]);
        }
#pragma unroll
        for (int j = 0; j < 4; ++j)
            tB[(j * T + (tid & 15)) * 20 + (tid >> 4)] = (float)pb[j];
        __syncthreads();
        if (st + 1 < NSUB) LOADG((st + 1) * T);   // prefetch next sub-tile

        const signed char* suc = (const signed char*)su_i;
        const signed char* sdc = (const signed char*)sd_i;
#pragma unroll
        for (int k = 0; k < T; ++k) {
            const float uf    = (float)suc[bcol + k] * u_s;
            const float delta = softplus_f((float)sdc[bcol + k] * dt_s + dtb);
            const float w     = delta * uf * B_s;
            S += delta;
            const float4* bt = (const float4*)&tB[(brow + k) * 20];
            const float4 B0 = bt[0], B1 = bt[1], B2 = bt[2], B3 = bt[3];
            const float Bt[NST] = {B0.x,B0.y,B0.z,B0.w, B1.x,B1.y,B1.z,B1.w,
                                   B2.x,B2.y,B2.z,B2.w, B3.x,B3.y,B3.z,B3.w};
#pragma unroll
            for (int n = 0; n < NST; ++n)
                x[n] = __builtin_fmaf(__builtin_amdgcn_exp2f(A2[n] * delta), x[n], w * Bt[n]);
        }
        __syncthreads();
    }

    Sbuf[(size_t)chunk * SCANS + scan] = S;
    float4* Xo = (float4*)(Xbuf + ((size_t)chunk * SCANS + scan) * NST);
#pragma unroll
    for (int q = 0; q < 4; ++q)
        Xo[q] = make_float4(x[4*q], x[4*q+1], x[4*q+2], x[4*q+3]);
}

// ---------------- Combine: fold summaries, write init states in-place ----------------
__global__ __launch_bounds__(256) void qs_combine(
    const int* __restrict__ A_log, const float* __restrict__ A_sp,
    const float* __restrict__ Sbuf, float* __restrict__ Xbuf)
{
    const int idx  = blockIdx.x * 256 + threadIdx.x;   // flat (scan, n)
    const int scan = idx >> 4, n = idx & 15;
    const int d    = scan & (DIM - 1);
    const float A2 = -__builtin_amdgcn_exp2f(
        (float)A_log[d * NST + n] * ((*A_sp) * LOG2E)) * LOG2E;
    float x = 0.f;
#pragma unroll
    for (int c = 0; c < K; ++c) {
        const size_t off = (size_t)c * (SCANS * NST) + idx;
        const float Xe = Xbuf[off];
        const float P  = __builtin_amdgcn_exp2f(A2 * Sbuf[(size_t)c * SCANS + scan]);
        Xbuf[off] = x;                                  // init state for chunk c
        x = __builtin_fmaf(P, x, Xe);
    }
}

// ---------------- Phase 2: rerun with true init, emit output ----------------
__global__ __launch_bounds__(256, 3) void qs_phase2(
    const int* __restrict__ u,  const int* __restrict__ dt,
    const int* __restrict__ Bm, const int* __restrict__ Cm,
    const int* __restrict__ z,  const int* __restrict__ A_log,
    const int* __restrict__ Dv, const int* __restrict__ dt_bias,
    const float* __restrict__ u_sp,  const float* __restrict__ dt_sp,
    const float* __restrict__ A_sp,  const float* __restrict__ B_sp,
    const float* __restrict__ C_sp,  const float* __restrict__ z_sp,
    const float* __restrict__ D_sp,  const float* __restrict__ dtb_sp,
    const float* __restrict__ XI, float* __restrict__ out)
{
    const int tid = threadIdx.x;
    const int cg  = blockIdx.x >> 7;
    const int sg  = blockIdx.x & 127;
    const int scan  = sg * SPB + (tid & 63);
    const int chunk = cg * CPB + (tid >> 6);
    const int d  = scan & (DIM - 1);
    const int bb = scan >> 12;

    __shared__ int   su_i[256 * 5];
    __shared__ int   sd_i[256 * 5];
    __shared__ int   sz_i[256 * 5];
    __shared__ float so_f[256 * 17];          // out staging, stride 17 (conflict-free)
    __shared__ float tBC[2][CPB * T * 20];    // B and C tiles

    const float u_s = *u_sp, dt_s = *dt_sp, A_s = *A_sp, B_s = *B_sp;
    const float C_s = *C_sp, z_s  = *z_sp,  D_s = *D_sp, dtb_s = *dtb_sp;
    LOAD_A2();
    const float dtb = (float)dt_bias[d] * dtb_s;
    const float Dd  = (float)Dv[d] * D_s;

    // true init state for this thread's chunk
    float x[NST];
    {
        const float4* xi = (const float4*)(XI + ((size_t)chunk * SCANS + scan) * NST);
        const float4 x0 = xi[0], x1 = xi[1], x2 = xi[2], x3 = xi[3];
        const float xin[NST] = {x0.x,x0.y,x0.z,x0.w, x1.x,x1.y,x1.z,x1.w,
                                x2.x,x2.y,x2.z,x2.w, x3.x,x3.y,x3.z,x3.w};
#pragma unroll
        for (int n = 0; n < NST; ++n) x[n] = xin[n];
    }

    const int lr = tid >> 2, lq = tid & 3;
    size_t gb[4];
#pragma unroll
    for (int p = 0; p < 4; ++p)
        gb[p] = (size_t)(sg * SPB + lr) * LSEQ + (size_t)(cg * CPB + p) * LC + 4 * lq;
    const size_t bcb = ((size_t)bb * NST + (tid >> 4)) * LSEQ + cg * (CPB * LC) + (tid & 15);

    int4 pu[4], pd[4], pz[4]; int pb[4], pc[4];
    auto LOADG = [&](int tt0) {
#pragma unroll
        for (int p = 0; p < 4; ++p) {
            pu[p] = *(const int4*)(u  + gb[p] + tt0);
            pd[p] = *(const int4*)(dt + gb[p] + tt0);
            pz[p] = *(const int4*)(z  + gb[p] + tt0);
        }
#pragma unroll
        for (int j = 0; j < 4; ++j) {
            pb[j] = Bm[bcb + j * LC + tt0];
            pc[j] = Cm[bcb + j * LC + tt0];
        }
    };

    const int bcol = tid * 20;
    const int brow = (tid >> 6) * T;

    LOADG(0);
    for (int st = 0; st < NSUB; ++st) {
#pragma unroll
        for (int p = 0; p < 4; ++p) {
            su_i[5 * (p * 64 + lr) + lq] = pack8(pu[p]);
            sd_i[5 * (p * 64 + lr) + lq] = pack8(pd[p]);
            sz_i[5 * (p * 64 + lr) + lq] = pack8(pz[p]);
        }
#pragma unroll
        for (int j = 0; j < 4; ++j) {
            tBC[0][(j * T + (tid & 15)) * 20 + (tid >> 4)] = (float)pb[j];
            tBC[1][(j * T + (tid & 15)) * 20 + (tid >> 4)] = (float)pc[j];
        }
        __syncthreads();
        if (st + 1 < NSUB) LOADG((st + 1) * T);   // prefetch hidden under compute

        const signed char* suc = (const signed char*)su_i;
        const signed char* sdc = (const signed char*)sd_i;
        const signed char* szc = (const signed char*)sz_i;
#pragma unroll
        for (int k = 0; k < T; ++k) {
            const float uf    = (float)suc[bcol + k] * u_s;
            const float delta = softplus_f((float)sdc[bcol + k] * dt_s + dtb);
            const float w     = delta * uf * B_s;
            const float zf    = (float)szc[bcol + k] * z_s;
            const float gate  = zf * __builtin_amdgcn_rcpf(
                                    1.f + __builtin_amdgcn_exp2f(-zf * LOG2E));
            const float4* bt = (const float4*)&tBC[0][(brow + k) * 20];
            const float4* ct = (const float4*)&tBC[1][(brow + k) * 20];
            const float4 B0 = bt[0], B1 = bt[1], B2 = bt[2], B3 = bt[3];
            const float4 C0 = ct[0], C1 = ct[1], C2 = ct[2], C3 = ct[3];
            const float Bt[NST] = {B0.x,B0.y,B0.z,B0.w, B1.x,B1.y,B1.z,B1.w,
                                   B2.x,B2.y,B2.z,B2.w, B3.x,B3.y,B3.z,B3.w};
            const float Ct[NST] = {C0.x,C0.y,C0.z,C0.w, C1.x,C1.y,C1.z,C1.w,
                                   C2.x,C2.y,C2.z,C2.w, C3.x,C3.y,C3.z,C3.w};
            float y = 0.f;
#pragma unroll
            for (int n = 0; n < NST; ++n) {
                x[n] = __builtin_fmaf(__builtin_amdgcn_exp2f(A2[n] * delta), x[n], w * Bt[n]);
                y    = __builtin_fmaf(x[n], Ct[n], y);
            }
            so_f[tid * 17 + k] = __builtin_fmaf(y, C_s, Dd * uf) * gate;
        }
        __syncthreads();

        // cooperative coalesced out store (reads pre-sync1 of next iter: safe)
#pragma unroll
        for (int p = 0; p < 4; ++p) {
            const int r = p * 64 + lr;
            const float4 v = make_float4(so_f[r * 17 + 4 * lq + 0],
                                         so_f[r * 17 + 4 * lq + 1],
                                         so_f[r * 17 + 4 * lq + 2],
                                         so_f[r * 17 + 4 * lq + 3]);
            *(float4*)(out + gb[p] + st * T) = v;
        }
    }
}

extern "C" void kernel_launch(void* const* d_in, const int* in_sizes, int n_in,
                              void* d_out, int out_size, void* d_ws, size_t ws_size,
                              hipStream_t stream) {
    const int* u   = (const int*)d_in[0];
    const int* dt  = (const int*)d_in[1];
    const int* Bm  = (const int*)d_in[2];
    const int* Cm  = (const int*)d_in[3];
    const int* z   = (const int*)d_in[4];
    const int* Al  = (const int*)d_in[5];
    const int* Dv  = (const int*)d_in[6];
    const int* dtb = (const int*)d_in[7];
    const float* u_sp = (const float*)d_in[8],  * dt_sp = (const float*)d_in[9];
    const float* A_sp = (const float*)d_in[10], * B_sp  = (const float*)d_in[11];
    const float* C_sp = (const float*)d_in[12], * z_sp  = (const float*)d_in[13];
    const float* D_sp = (const float*)d_in[14], * dtb_sp= (const float*)d_in[15];

    float* Xbuf = (float*)d_ws;                          // K*SCANS*NST f32 = 16.8 MiB
    float* Sbuf = Xbuf + (size_t)K * SCANS * NST;        // K*SCANS f32 = 1 MiB

    dim3 blk(256);
    qs_phase1<<<dim3(8 * 128), blk, 0, stream>>>(u, dt, Bm, Al, dtb,
        u_sp, dt_sp, A_sp, B_sp, dtb_sp, Sbuf, Xbuf);
    qs_combine<<<dim3(SCANS * NST / 256), blk, 0, stream>>>(Al, A_sp, Sbuf, Xbuf);
    qs_phase2<<<dim3(8 * 128), blk, 0, stream>>>(u, dt, Bm, Cm, z, Al, Dv, dtb,
        u_sp, dt_sp, A_sp, B_sp, C_sp, z_sp, D_sp, dtb_sp, Xbuf, (float*)d_out);
}